// Round 3
// baseline (101.733 us; speedup 1.0000x reference)
//
#include <hip/hip_runtime.h>

#define NB 4
#define DD 128
#define NN 4096
#define INV_T 14.285714285714285f

typedef __attribute__((ext_vector_type(8))) short bf16x8;
typedef __attribute__((ext_vector_type(4))) float f32x4;

static __device__ __forceinline__ unsigned short f32_to_bf16(float x){
  unsigned u = __float_as_uint(x);
  u += 0x7fffu + ((u >> 16) & 1u);   // RNE
  return (unsigned short)(u >> 16);
}

// async 16B global->LDS DMA (lds dest wave-uniform; lands at +lane*16)
static __device__ __forceinline__ void async_copy16(const uint4* g, uint4* l){
  __builtin_amdgcn_global_load_lds(
      (const __attribute__((address_space(1))) unsigned int*)g,
      (__attribute__((address_space(3))) unsigned int*)l, 16, 0, 0);
}

// Kernel A: L1-normalize + transpose [B][128][N] fp32 -> [B][N][128] bf16
// 16B chunks stored XOR-swizzled (chunk c of row r at slot c^(r&15)) so a
// linear global_load_lds in simexp lands pre-swizzled (bank-conflict-free).
__global__ __launch_bounds__(256) void norm_kernel(const float* __restrict__ fq,
                                                   const float* __restrict__ fk,
                                                   unsigned short* __restrict__ qn,
                                                   unsigned short* __restrict__ kn){
  const float* src = blockIdx.z ? fk : fq;
  unsigned short* dst = blockIdx.z ? kn : qn;
  int b = blockIdx.y;
  int n0 = blockIdx.x * 64;
  __shared__ float sT[64][129];   // stride 129: conflict-free col writes/row reads
  __shared__ float red[4][64];
  __shared__ float srd[64];
  int t = threadIdx.x;
  const float* sb = src + (size_t)b*DD*NN + n0;
  // float4 loads: 8 VMEM insts/thread instead of 32 (issue-bound phase)
  #pragma unroll
  for (int it = 0; it < 8; ++it){
    int idx = it*256 + t;
    int d = idx >> 4, c4 = idx & 15;
    const float4 v = *reinterpret_cast<const float4*>(sb + (size_t)d*NN + c4*4);
    sT[c4*4+0][d] = v.x;
    sT[c4*4+1][d] = v.y;
    sT[c4*4+2][d] = v.z;
    sT[c4*4+3][d] = v.w;
  }
  __syncthreads();
  {
    int nn = t & 63, part = t >> 6;
    float s = 0.f;
    #pragma unroll
    for (int j = 0; j < 32; ++j) s += fabsf(sT[nn][part*32 + j]);
    red[part][nn] = s;
  }
  __syncthreads();
  if (t < 64){
    float dsum = red[0][t] + red[1][t] + red[2][t] + red[3][t];
    srd[t] = 1.f / fmaxf(dsum, 1e-12f);
  }
  __syncthreads();
  unsigned short* db = dst + ((size_t)b*NN + n0)*DD;
  #pragma unroll
  for (int it = 0; it < 4; ++it){
    int c = it*256 + t;
    int row = c >> 4, dc = c & 15;
    float r = srd[row];
    unsigned v[4];
    #pragma unroll
    for (int p = 0; p < 4; ++p){
      unsigned short lo = f32_to_bf16(sT[row][dc*8 + p*2    ] * r);
      unsigned short hi = f32_to_bf16(sT[row][dc*8 + p*2 + 1] * r);
      v[p] = (unsigned)lo | ((unsigned)hi << 16);
    }
    uint4 pack = make_uint4(v[0], v[1], v[2], v[3]);
    int sw = dc ^ (row & 15);     // global pre-swizzle
    *reinterpret_cast<uint4*>(db + (size_t)row*DD + sw*8) = pack;
  }
}

// Kernel B: partial[y][b][row] = sum over this col-block of exp(sim/T),
// with the diagonal element skipped exactly (ref diag contributes
// exp(-10/0.07) -> 0 in fp32). block tile 128 rows x 1024 cols, grid (32,4,B).
__global__ __launch_bounds__(256,2) void simexp_kernel(const unsigned short* __restrict__ qn,
                                                       const unsigned short* __restrict__ kn,
                                                       float* __restrict__ partial){
  __shared__ uint4 sQ[2048];   // 32 KB
  __shared__ uint4 sK[2048];   // 32 KB
  __shared__ float sred[4][64];
  int t = threadIdx.x;
  int w = t >> 6, lane = t & 63;
  int quad = lane >> 4, l16 = lane & 15;
  int b  = blockIdx.z;
  int r0 = blockIdx.x * 128;
  int c0 = blockIdx.y * 1024;
  const uint4* gq = reinterpret_cast<const uint4*>(qn + ((size_t)b*NN + r0)*DD);
  const uint4* gk = reinterpret_cast<const uint4*>(kn + ((size_t)b*NN + c0)*DD);
  #pragma unroll
  for (int i = 0; i < 8; ++i)
    async_copy16(gq + w*512 + i*64 + lane, &sQ[w*512 + i*64]);
  #pragma unroll
  for (int i = 0; i < 8; ++i)
    async_copy16(gk + w*512 + i*64 + lane, &sK[w*512 + i*64]);
  __syncthreads();

  int wr = (w >> 1)*64, wc = (w & 1)*64;   // wave quadrant
  // diag of the full sim matrix lives in block (x, y==x>>3), k-tile x&7,
  // waves with wr==wc, acc elements i==j && l16==quad*4+r
  bool dWave = (blockIdx.y == (blockIdx.x >> 3)) && (wr == wc);
  int diagKt = blockIdx.x & 7;

  bf16x8 a[4][4];
  #pragma unroll
  for (int i = 0; i < 4; ++i){
    int row = wr + i*16 + l16;
    #pragma unroll
    for (int ks = 0; ks < 4; ++ks)
      a[i][ks] = __builtin_bit_cast(bf16x8, sQ[row*16 + ((ks*4 + quad) ^ l16)]);
  }
  float rsum[16];
  #pragma unroll
  for (int s = 0; s < 16; ++s) rsum[s] = 0.f;

  for (int kt = 0; kt < 8; ++kt){
    if (kt){
      __syncthreads();
      #pragma unroll
      for (int i = 0; i < 8; ++i)
        async_copy16(gk + kt*2048 + w*512 + i*64 + lane, &sK[w*512 + i*64]);
      __syncthreads();
    }
    f32x4 acc[4][4];
    #pragma unroll
    for (int i = 0; i < 4; ++i)
      #pragma unroll
      for (int j = 0; j < 4; ++j)
        acc[i][j] = (f32x4){0.f, 0.f, 0.f, 0.f};
    #pragma unroll
    for (int ks = 0; ks < 4; ++ks){
      bf16x8 bfr[4];
      #pragma unroll
      for (int j = 0; j < 4; ++j){
        int col = wc + j*16 + l16;
        bfr[j] = __builtin_bit_cast(bf16x8, sK[col*16 + ((ks*4 + quad) ^ l16)]);
      }
      #pragma unroll
      for (int i = 0; i < 4; ++i)
        #pragma unroll
        for (int j = 0; j < 4; ++j)
          acc[i][j] = __builtin_amdgcn_mfma_f32_16x16x32_bf16(a[i][ks], bfr[j], acc[i][j], 0, 0, 0);
    }
    bool dk = dWave && (kt == diagKt);
    // epilogue: C[row=i*16+quad*4+r][col=j*16+l16]
    #pragma unroll
    for (int i = 0; i < 4; ++i)
      #pragma unroll
      for (int j = 0; j < 4; ++j)
        #pragma unroll
        for (int r = 0; r < 4; ++r){
          float e = __expf(acc[i][j][r] * INV_T);
          if (dk && (i == j) && (l16 == quad*4 + r)) e = 0.f;   // exact diag skip
          rsum[i*4 + r] += e;
        }
  }
  // per-wave col reduce, then combine the two wc-halves via LDS, plain store
  #pragma unroll
  for (int s = 0; s < 16; ++s){
    float v = rsum[s];
    v += __shfl_xor(v, 1, 64);
    v += __shfl_xor(v, 2, 64);
    v += __shfl_xor(v, 4, 64);
    v += __shfl_xor(v, 8, 64);
    if (l16 == 0) sred[w][(s >> 2)*16 + quad*4 + (s & 3)] = v;
  }
  __syncthreads();
  if (t < 128){
    int half = t >> 6;   // 0: waves 0,1 (rows 0-63); 1: waves 2,3 (rows 64-127)
    float v = sred[half*2][t & 63] + sred[half*2 + 1][t & 63];
    partial[((size_t)blockIdx.y*NB + b)*NN + r0 + t] = v;
  }
}

// Kernel C: single block; rowsum = sum of 4 partials; loss = mean log1p(rowsum)
__global__ __launch_bounds__(1024) void final_kernel(const float* __restrict__ partial,
                                                     float* __restrict__ out){
  __shared__ float swave[16];
  int t = threadIdx.x;
  float acc = 0.f;
  #pragma unroll
  for (int i = 0; i < 16; ++i){
    int idx = i*1024 + t;
    float rs = partial[idx] + partial[16384 + idx] + partial[32768 + idx] + partial[49152 + idx];
    acc += log1pf(rs);
  }
  acc += __shfl_xor(acc, 1, 64);
  acc += __shfl_xor(acc, 2, 64);
  acc += __shfl_xor(acc, 4, 64);
  acc += __shfl_xor(acc, 8, 64);
  acc += __shfl_xor(acc, 16, 64);
  acc += __shfl_xor(acc, 32, 64);
  if ((t & 63) == 0) swave[t >> 6] = acc;
  __syncthreads();
  if (t == 0){
    float s = 0.f;
    #pragma unroll
    for (int i = 0; i < 16; ++i) s += swave[i];
    out[0] = s * (1.f / (float)(NB*NN));
  }
}

extern "C" void kernel_launch(void* const* d_in, const int* in_sizes, int n_in,
                              void* d_out, int out_size, void* d_ws, size_t ws_size,
                              hipStream_t stream){
  const float* fq = (const float*)d_in[0];
  const float* fk = (const float*)d_in[1];
  unsigned short* qn = (unsigned short*)d_ws;                  // 4 MB bf16 [B][N][D] (chunk-swizzled)
  unsigned short* kn = qn + (size_t)NB*NN*DD;                  // 4 MB
  float* partial = (float*)(kn + (size_t)NB*NN*DD);            // 256 KB [4][B][N]
  float* out = (float*)d_out;

  norm_kernel<<<dim3(NN/64, NB, 2), 256, 0, stream>>>(fq, fk, qn, kn);
  simexp_kernel<<<dim3(NN/128, 4, NB), 256, 0, stream>>>(qn, kn, partial);
  final_kernel<<<1, 1024, 0, stream>>>(partial, out);
}